// Round 1
// baseline (2727.861 us; speedup 1.0000x reference)
//
#include <hip/hip_runtime.h>
#include <cstdint>
#include <cstddef>

#define S_LEN 2048
#define NH 8
#define NKVH 2
#define HD 256

// ---------------------------------------------------------------------------
// Classic 128x128 f32 GEMM, BK=8, 256 threads, 8x8 accum per thread.
// A [M,K] row-major, B [K,N] row-major, C [M,N] row-major. All dims %128==0
// except K which must be %8==0 (true for all our shapes: K in {2048}, N in
// {2048,512}).
// ---------------------------------------------------------------------------
__global__ __launch_bounds__(256) void sgemm128(
    const float* __restrict__ A, const float* __restrict__ B,
    float* __restrict__ C, int M, int N, int K) {
  __shared__ float As[8][128];  // [k][m]
  __shared__ float Bs[8][128];  // [k][n]
  const int tid = threadIdx.x;
  const int bm = blockIdx.y * 128;
  const int bn = blockIdx.x * 128;
  const int tx = tid & 15;
  const int ty = tid >> 4;
  const int a_row = tid >> 1;        // 0..127
  const int a_k4 = (tid & 1) * 4;    // 0 or 4
  const int b_k = tid >> 5;          // 0..7
  const int b_col = (tid & 31) * 4;  // 0..124
  const float* Ap = A + (size_t)(bm + a_row) * K + a_k4;
  const float* Bp = B + (size_t)b_k * N + bn + b_col;
  float acc[8][8];
#pragma unroll
  for (int i = 0; i < 8; ++i)
#pragma unroll
    for (int j = 0; j < 8; ++j) acc[i][j] = 0.f;

  for (int k0 = 0; k0 < K; k0 += 8) {
    float4 av = *(const float4*)(Ap + k0);
    float4 bv = *(const float4*)(Bp + (size_t)k0 * N);
    __syncthreads();  // protect LDS from previous iteration's readers
    As[a_k4 + 0][a_row] = av.x;
    As[a_k4 + 1][a_row] = av.y;
    As[a_k4 + 2][a_row] = av.z;
    As[a_k4 + 3][a_row] = av.w;
    *(float4*)&Bs[b_k][b_col] = bv;
    __syncthreads();
#pragma unroll
    for (int k = 0; k < 8; ++k) {
      float ar[8], br[8];
      *(float4*)&ar[0] = *(const float4*)&As[k][ty * 8];
      *(float4*)&ar[4] = *(const float4*)&As[k][ty * 8 + 4];
      *(float4*)&br[0] = *(const float4*)&Bs[k][tx * 8];
      *(float4*)&br[4] = *(const float4*)&Bs[k][tx * 8 + 4];
#pragma unroll
      for (int i = 0; i < 8; ++i)
#pragma unroll
        for (int j = 0; j < 8; ++j) acc[i][j] = fmaf(ar[i], br[j], acc[i][j]);
    }
  }
#pragma unroll
  for (int i = 0; i < 8; ++i) {
    float* Cp = C + (size_t)(bm + ty * 8 + i) * N + bn + tx * 8;
    *(float4*)Cp = make_float4(acc[i][0], acc[i][1], acc[i][2], acc[i][3]);
    *(float4*)(Cp + 4) = make_float4(acc[i][4], acc[i][5], acc[i][6], acc[i][7]);
  }
}

// ---------------------------------------------------------------------------
// Per-(b,s,head) RMSNorm (+optional scale) and RoPE, IN PLACE on the
// projection buffers. slot 0..7 = Q heads (scale+rope), 8..9 = K heads
// (scale+rope), 10..11 = V heads (plain rmsnorm).
// RoPE: half-split rotation, angle = s * 10000^(-fi/128), fi = d % 128.
// ---------------------------------------------------------------------------
__global__ __launch_bounds__(256) void rmsrope(
    float* __restrict__ qproj, float* __restrict__ kproj,
    float* __restrict__ vproj, const float* __restrict__ q_scale,
    const float* __restrict__ k_scale) {
  const int t = threadIdx.x;
  const int blk = blockIdx.x;
  const int slot = blk % 12;
  const int bs = blk / 12;
  const int s = bs & (S_LEN - 1);
  float* ptr;
  const float* scale;
  bool rope;
  if (slot < 8) {
    ptr = qproj + (size_t)bs * 2048 + slot * 256;
    scale = q_scale;
    rope = true;
  } else if (slot < 10) {
    ptr = kproj + (size_t)bs * 512 + (slot - 8) * 256;
    scale = k_scale;
    rope = true;
  } else {
    ptr = vproj + (size_t)bs * 512 + (slot - 10) * 256;
    scale = nullptr;
    rope = false;
  }
  const float x = ptr[t];
  float ss = x * x;
#pragma unroll
  for (int off = 32; off; off >>= 1) ss += __shfl_down(ss, off);
  __shared__ float red[4];
  __shared__ float tot;
  if ((t & 63) == 0) red[t >> 6] = ss;
  __syncthreads();
  if (t == 0) tot = red[0] + red[1] + red[2] + red[3];
  __syncthreads();
  const float inv = rsqrtf(tot * (1.f / 256.f) + 1e-6f);
  float n = x * inv;
  if (scale) n *= scale[t];
  if (!rope) {
    ptr[t] = n;
    return;
  }
  __shared__ float sh[256];
  sh[t] = n;
  __syncthreads();
  const int fi = t & 127;
  // inv_freq = 10000^(-fi/128) = exp(fi * (-ln(10000)/128))
  const float invf = expf((float)fi * (-9.210340371976184f / 128.f));
  const float ang = (float)s * invf;
  float sv, cv;
  sincosf(ang, &sv, &cv);
  float o;
  if (t < 128)
    o = sh[t] * cv - sh[t + 128] * sv;  // x1*cos - x2*sin
  else
    o = sh[t] * cv + sh[t - 128] * sv;  // x2*cos + x1*sin
  ptr[t] = o;
}

// ---------------------------------------------------------------------------
// Sliding-window causal attention (scale=1.0). One block = 8 consecutive
// queries of one (b,h). Window for query i: j in [i-511, i]. Union window of
// the 8-query tile: [max(0,i0-511), i0+7], nk <= 519 keys.
// qproj layout [B*S][2048] (col h*256+d), k/vproj [B*S][512] (col kvh*256+d).
// Output attn [B*S][2048] f32 (feeds O-proj GEMM).
// ---------------------------------------------------------------------------
__global__ __launch_bounds__(256) void attn_win(
    const float* __restrict__ qproj, const float* __restrict__ kproj,
    const float* __restrict__ vproj, float* __restrict__ attn) {
  __shared__ float sq[8 * 264];  // padded Q tile [8][264]
  __shared__ float sc[8 * 520];  // scores/probs [8][520]
  __shared__ float rv[8];        // 1/sum per row
  const int t = threadIdx.x;
  const int blk = blockIdx.x;
  const int i0 = (blk & 255) * 8;
  const int h = (blk >> 8) & 7;
  const int b = blk >> 11;
  const int kvh = h >> 2;
  const int jlo = (i0 >= 512) ? (i0 - 511) : 0;
  const int nk = i0 + 8 - jlo;  // <= 519
  const float* qbase = qproj + ((size_t)b * S_LEN) * 2048 + h * 256;
  const float* kbase = kproj + ((size_t)b * S_LEN) * 512 + kvh * 256;
  const float* vbase = vproj + ((size_t)b * S_LEN) * 512 + kvh * 256;

  // load Q tile (8 rows x 256) as float4
  for (int p = t; p < 512; p += 256) {
    const int q = p >> 6;
    const int d4 = p & 63;
    float4 v = *(const float4*)(qbase + (size_t)(i0 + q) * 2048 + d4 * 4);
    *(float4*)&sq[q * 264 + d4 * 4] = v;
  }
  __syncthreads();

  // scores: pair index p -> (q = p&7, kk = p>>3); 8 threads share one K row
  for (int p = t; p < (nk << 3); p += 256) {
    const int q = p & 7;
    const int kk = p >> 3;
    const float* krow = kbase + (size_t)(jlo + kk) * 512;
    const float* qr = &sq[q * 264];
    float dot = 0.f;
#pragma unroll
    for (int d = 0; d < 256; d += 8) {
      float4 k0 = *(const float4*)(krow + d);
      float4 k1 = *(const float4*)(krow + d + 4);
      float4 q0 = *(const float4*)(qr + d);
      float4 q1 = *(const float4*)(qr + d + 4);
      dot += q0.x * k0.x + q0.y * k0.y + q0.z * k0.z + q0.w * k0.w;
      dot += q1.x * k1.x + q1.y * k1.y + q1.z * k1.z + q1.w * k1.w;
    }
    sc[q * 520 + kk] = dot;
  }
  __syncthreads();

  // softmax: wave wv handles rows wv and wv+4
  const int wv = t >> 6, ln = t & 63;
  for (int rq = wv; rq < 8; rq += 4) {
    const int i = i0 + rq;
    float m = -1e30f;
    for (int kk = ln; kk < nk; kk += 64) {
      const int j = jlo + kk;
      float s_ = sc[rq * 520 + kk];
      if (j > i || i - j > 511) {
        s_ = -1e30f;
        sc[rq * 520 + kk] = s_;
      }
      m = fmaxf(m, s_);
    }
#pragma unroll
    for (int off = 32; off; off >>= 1) m = fmaxf(m, __shfl_down(m, off));
    m = __shfl(m, 0);
    float sum = 0.f;
    for (int kk = ln; kk < nk; kk += 64) {
      const float pp = __expf(sc[rq * 520 + kk] - m);  // invalid -> exp(-1e30)=0
      sc[rq * 520 + kk] = pp;
      sum += pp;
    }
#pragma unroll
    for (int off = 32; off; off >>= 1) sum += __shfl_down(sum, off);
    if (ln == 0) rv[rq] = 1.f / sum;
  }
  __syncthreads();

  // PV: thread t -> (q = t>>5, d0 = (t&31)*8), 8 output dims each
  const int q = t >> 5;
  const int d0 = (t & 31) * 8;
  float o[8];
#pragma unroll
  for (int j = 0; j < 8; ++j) o[j] = 0.f;
  const float* pr = &sc[q * 520];
  for (int kk = 0; kk < nk; ++kk) {
    const float pp = pr[kk];
    const float* vrow = vbase + (size_t)(jlo + kk) * 512 + d0;
    float4 va = *(const float4*)vrow;
    float4 vb = *(const float4*)(vrow + 4);
    o[0] = fmaf(pp, va.x, o[0]);
    o[1] = fmaf(pp, va.y, o[1]);
    o[2] = fmaf(pp, va.z, o[2]);
    o[3] = fmaf(pp, va.w, o[3]);
    o[4] = fmaf(pp, vb.x, o[4]);
    o[5] = fmaf(pp, vb.y, o[5]);
    o[6] = fmaf(pp, vb.z, o[6]);
    o[7] = fmaf(pp, vb.w, o[7]);
  }
  const float r = rv[q];
  float* orow = attn + (size_t)(b * S_LEN + i0 + q) * 2048 + h * 256 + d0;
  *(float4*)orow = make_float4(o[0] * r, o[1] * r, o[2] * r, o[3] * r);
  *(float4*)(orow + 4) = make_float4(o[4] * r, o[5] * r, o[6] * r, o[7] * r);
}

// ---------------------------------------------------------------------------
// inputs: 0 hidden_states [2,2048,2048] f32, 1 attention_mask (unused; it is
// exactly the causal tril which we apply analytically together with the
// window band), 2 Wq [2048,2048], 3 Wk [2048,512], 4 Wv [2048,512],
// 5 Wo [2048,2048], 6 q_scale [256], 7 k_scale [256].
// output: [2,2048,2048] f32.
// ---------------------------------------------------------------------------
extern "C" void kernel_launch(void* const* d_in, const int* in_sizes, int n_in,
                              void* d_out, int out_size, void* d_ws,
                              size_t ws_size, hipStream_t stream) {
  (void)in_sizes;
  (void)n_in;
  (void)out_size;
  (void)ws_size;
  const float* X = (const float*)d_in[0];
  const float* Wq = (const float*)d_in[2];
  const float* Wk = (const float*)d_in[3];
  const float* Wv = (const float*)d_in[4];
  const float* Wo = (const float*)d_in[5];
  const float* qs = (const float*)d_in[6];
  const float* ks = (const float*)d_in[7];
  float* out = (float*)d_out;
  char* ws = (char*)d_ws;

  const int M = 2 * S_LEN;  // 4096 rows
  float* qproj = (float*)(ws);               // 4096*2048*4 = 33554432 B
  float* kproj = (float*)(ws + 33554432);    // 4096* 512*4 =  8388608 B
  float* vproj = (float*)(ws + 41943040);    // 4096* 512*4 =  8388608 B
  float* attn = (float*)(ws + 50331648);     // 4096*2048*4 = 33554432 B
  // total ws use: 83886080 B

  // QKV projections
  sgemm128<<<dim3(2048 / 128, M / 128), 256, 0, stream>>>(X, Wq, qproj, M,
                                                          2048, 2048);
  sgemm128<<<dim3(512 / 128, M / 128), 256, 0, stream>>>(X, Wk, kproj, M, 512,
                                                         2048);
  sgemm128<<<dim3(512 / 128, M / 128), 256, 0, stream>>>(X, Wv, vproj, M, 512,
                                                         2048);
  // RMSNorm (+scale) + RoPE, in place
  rmsrope<<<M * 12, 256, 0, stream>>>(qproj, kproj, vproj, qs, ks);
  // sliding-window causal attention
  attn_win<<<2 * NH * (S_LEN / 8), 256, 0, stream>>>(qproj, kproj, vproj,
                                                     attn);
  // output projection
  sgemm128<<<dim3(2048 / 128, M / 128), 256, 0, stream>>>(attn, Wo, out, M,
                                                          2048, 2048);
}

// Round 3
// 522.568 us; speedup vs baseline: 5.2201x; 5.2201x over previous
//
#include <hip/hip_runtime.h>
#include <cstdint>
#include <cstddef>

typedef unsigned short u16;
typedef float floatx4 __attribute__((ext_vector_type(4)));
typedef __bf16 bf16x8 __attribute__((ext_vector_type(8)));

__device__ __forceinline__ u16 f2bf(float f) {
  union { float f; unsigned u; } v;
  v.f = f;
  unsigned u = v.u;
  u += 0x7FFFu + ((u >> 16) & 1u);
  return (u16)(u >> 16);
}
__device__ __forceinline__ float bf2f(u16 h) {
  union { unsigned u; float f; } v;
  v.u = ((unsigned)h) << 16;
  return v.f;
}

#define GLL16(g, l)                                                       \
  __builtin_amdgcn_global_load_lds(                                       \
      (const __attribute__((address_space(1))) void*)(g),                 \
      (__attribute__((address_space(3))) void*)(l), 16, 0, 0)

// ---------------------------------------------------------------------------
// split f32 -> (hi, lo) bf16 pair, 8 elems/thread. x ~= hi + lo.
// ---------------------------------------------------------------------------
__global__ __launch_bounds__(256) void splitbf(const float* __restrict__ in,
                                               u16* __restrict__ oh,
                                               u16* __restrict__ ol, int n8) {
  int idx = blockIdx.x * 256 + threadIdx.x;
  if (idx >= n8) return;
  float x[8];
  *(float4*)&x[0] = *(const float4*)(in + (size_t)idx * 8);
  *(float4*)&x[4] = *(const float4*)(in + (size_t)idx * 8 + 4);
  u16 h[8], l[8];
#pragma unroll
  for (int j = 0; j < 8; ++j) {
    h[j] = f2bf(x[j]);
    l[j] = f2bf(x[j] - bf2f(h[j]));
  }
  *(uint4*)(oh + (size_t)idx * 8) = *(const uint4*)h;
  *(uint4*)(ol + (size_t)idx * 8) = *(const uint4*)l;
}

// ---------------------------------------------------------------------------
// transpose f32 [R][C] -> bf16 hi/lo [C][R].  R,C % 64 == 0.
// ---------------------------------------------------------------------------
__global__ __launch_bounds__(256) void wtrans_s(const float* __restrict__ in,
                                                u16* __restrict__ oh,
                                                u16* __restrict__ ol, int R,
                                                int C) {
  __shared__ float T[64][65];
  const int t = threadIdx.x;
  const int r0 = blockIdx.y * 64;
  const int c0 = blockIdx.x * 64;
#pragma unroll
  for (int p = 0; p < 4; ++p) {
    const int rl = (t >> 4) + p * 16;
    const int c4 = (t & 15) * 4;
    float4 v = *(const float4*)(in + (size_t)(r0 + rl) * C + c0 + c4);
    T[c4 + 0][rl] = v.x;
    T[c4 + 1][rl] = v.y;
    T[c4 + 2][rl] = v.z;
    T[c4 + 3][rl] = v.w;
  }
  __syncthreads();
#pragma unroll
  for (int p = 0; p < 2; ++p) {
    const int cl = (t >> 3) + p * 32;
    const int r8 = (t & 7) * 8;
    u16 h[8], l[8];
#pragma unroll
    for (int j = 0; j < 8; ++j) {
      const float x = T[cl][r8 + j];
      h[j] = f2bf(x);
      l[j] = f2bf(x - bf2f(h[j]));
    }
    *(uint4*)(oh + (size_t)(c0 + cl) * R + r0 + r8) = *(const uint4*)h;
    *(uint4*)(ol + (size_t)(c0 + cl) * R + r0 + r8) = *(const uint4*)l;
  }
}

// ---------------------------------------------------------------------------
// transpose f32 [R][C] -> bf16 [C][R] (hi only), for Wo.
// ---------------------------------------------------------------------------
__global__ __launch_bounds__(256) void wtrans(const float* __restrict__ in,
                                              u16* __restrict__ out, int R,
                                              int C) {
  __shared__ u16 T[64][80];
  const int t = threadIdx.x;
  const int r0 = blockIdx.y * 64;
  const int c0 = blockIdx.x * 64;
#pragma unroll
  for (int p = 0; p < 4; ++p) {
    const int rl = (t >> 4) + p * 16;
    const int c4 = (t & 15) * 4;
    float4 v = *(const float4*)(in + (size_t)(r0 + rl) * C + c0 + c4);
    T[c4 + 0][rl] = f2bf(v.x);
    T[c4 + 1][rl] = f2bf(v.y);
    T[c4 + 2][rl] = f2bf(v.z);
    T[c4 + 3][rl] = f2bf(v.w);
  }
  __syncthreads();
#pragma unroll
  for (int p = 0; p < 2; ++p) {
    const int cl = (t >> 3) + p * 32;
    const int r8 = (t & 7) * 8;
    *(uint4*)(out + (size_t)(c0 + cl) * R + r0 + r8) =
        *(const uint4*)&T[cl][r8];
  }
}

// ---------------------------------------------------------------------------
// SPLIT bf16x3 MFMA GEMM: C f32 = (Ah+Al)[M,K] x (Bh+Bl)^T, B given as [N,K].
// hi*hi + hi*lo + lo*hi (lo*lo dropped, ~2^-16 relative). 128x128 tile, BK=32.
// ---------------------------------------------------------------------------
__global__ __launch_bounds__(256) void gemm_bf16s(
    const u16* __restrict__ Ah, const u16* __restrict__ Al,
    const u16* __restrict__ Bh, const u16* __restrict__ Bl,
    float* __restrict__ C, int M, int N, int K) {
  __shared__ u16 Ash[4096], Asl[4096], Bsh[4096], Bsl[4096];
  const int tid = threadIdx.x;
  const int lane = tid & 63;
  const int wid = tid >> 6;
  const int g = lane >> 4, lc = lane & 15;
  const int bm = blockIdx.y * 128, bn = blockIdx.x * 128;
  const int wr = (wid >> 1) * 64, wc = (wid & 1) * 64;
  const size_t aoff = (size_t)(bm + (tid >> 2)) * K + (tid & 3) * 8;
  const size_t boff = (size_t)(bn + (tid >> 2)) * K + (tid & 3) * 8;

  floatx4 acc[4][4];
#pragma unroll
  for (int i = 0; i < 4; ++i)
#pragma unroll
    for (int j = 0; j < 4; ++j) acc[i][j] = floatx4{0.f, 0.f, 0.f, 0.f};

  for (int k0 = 0; k0 < K; k0 += 32) {
    __syncthreads();
    GLL16(Ah + aoff + k0, Ash + tid * 8);
    GLL16(Ah + aoff + (size_t)64 * K + k0, Ash + 2048 + tid * 8);
    GLL16(Al + aoff + k0, Asl + tid * 8);
    GLL16(Al + aoff + (size_t)64 * K + k0, Asl + 2048 + tid * 8);
    GLL16(Bh + boff + k0, Bsh + tid * 8);
    GLL16(Bh + boff + (size_t)64 * K + k0, Bsh + 2048 + tid * 8);
    GLL16(Bl + boff + k0, Bsl + tid * 8);
    GLL16(Bl + boff + (size_t)64 * K + k0, Bsl + 2048 + tid * 8);
    __syncthreads();
    bf16x8 afh[4], afl[4], bfh[4], bfl[4];
#pragma unroll
    for (int m = 0; m < 4; ++m) {
      afh[m] = *(const bf16x8*)(Ash + (wr + m * 16 + lc) * 32 + g * 8);
      afl[m] = *(const bf16x8*)(Asl + (wr + m * 16 + lc) * 32 + g * 8);
    }
#pragma unroll
    for (int n = 0; n < 4; ++n) {
      bfh[n] = *(const bf16x8*)(Bsh + (wc + n * 16 + lc) * 32 + g * 8);
      bfl[n] = *(const bf16x8*)(Bsl + (wc + n * 16 + lc) * 32 + g * 8);
    }
#pragma unroll
    for (int m = 0; m < 4; ++m)
#pragma unroll
      for (int n = 0; n < 4; ++n) {
        acc[m][n] = __builtin_amdgcn_mfma_f32_16x16x32_bf16(afh[m], bfh[n],
                                                            acc[m][n], 0, 0, 0);
        acc[m][n] = __builtin_amdgcn_mfma_f32_16x16x32_bf16(afh[m], bfl[n],
                                                            acc[m][n], 0, 0, 0);
        acc[m][n] = __builtin_amdgcn_mfma_f32_16x16x32_bf16(afl[m], bfh[n],
                                                            acc[m][n], 0, 0, 0);
      }
  }
#pragma unroll
  for (int m = 0; m < 4; ++m)
#pragma unroll
    for (int n = 0; n < 4; ++n) {
      float* Cp = C + (size_t)(bm + wr + m * 16 + g * 4) * N + bn + wc +
                  n * 16 + lc;
#pragma unroll
      for (int r = 0; r < 4; ++r) Cp[(size_t)r * N] = acc[m][n][r];
    }
}

// ---------------------------------------------------------------------------
// plain bf16 MFMA GEMM (O-proj): C f32 = A[M,K] x Bt[N,K]^T.
// ---------------------------------------------------------------------------
__global__ __launch_bounds__(256) void gemm_bf16(const u16* __restrict__ A,
                                                 const u16* __restrict__ Bt,
                                                 float* __restrict__ C, int M,
                                                 int N, int K) {
  __shared__ u16 As[4096];
  __shared__ u16 Bs[4096];
  const int tid = threadIdx.x;
  const int lane = tid & 63;
  const int wid = tid >> 6;
  const int g = lane >> 4, lc = lane & 15;
  const int bm = blockIdx.y * 128, bn = blockIdx.x * 128;
  const int wr = (wid >> 1) * 64, wc = (wid & 1) * 64;
  const u16* Ag = A + (size_t)(bm + (tid >> 2)) * K + (tid & 3) * 8;
  const u16* Bg = Bt + (size_t)(bn + (tid >> 2)) * K + (tid & 3) * 8;

  floatx4 acc[4][4];
#pragma unroll
  for (int i = 0; i < 4; ++i)
#pragma unroll
    for (int j = 0; j < 4; ++j) acc[i][j] = floatx4{0.f, 0.f, 0.f, 0.f};

  for (int k0 = 0; k0 < K; k0 += 32) {
    __syncthreads();
    GLL16(Ag + k0, As + tid * 8);
    GLL16(Ag + (size_t)64 * K + k0, As + 2048 + tid * 8);
    GLL16(Bg + k0, Bs + tid * 8);
    GLL16(Bg + (size_t)64 * K + k0, Bs + 2048 + tid * 8);
    __syncthreads();
    bf16x8 af[4], bfr[4];
#pragma unroll
    for (int m = 0; m < 4; ++m)
      af[m] = *(const bf16x8*)(As + (wr + m * 16 + lc) * 32 + g * 8);
#pragma unroll
    for (int n = 0; n < 4; ++n)
      bfr[n] = *(const bf16x8*)(Bs + (wc + n * 16 + lc) * 32 + g * 8);
#pragma unroll
    for (int m = 0; m < 4; ++m)
#pragma unroll
      for (int n = 0; n < 4; ++n)
        acc[m][n] = __builtin_amdgcn_mfma_f32_16x16x32_bf16(af[m], bfr[n],
                                                            acc[m][n], 0, 0, 0);
  }
#pragma unroll
  for (int m = 0; m < 4; ++m)
#pragma unroll
    for (int n = 0; n < 4; ++n) {
      float* Cp = C + (size_t)(bm + wr + m * 16 + g * 4) * N + bn + wc +
                  n * 16 + lc;
#pragma unroll
      for (int r = 0; r < 4; ++r) Cp[(size_t)r * N] = acc[m][n][r];
    }
}

// ---------------------------------------------------------------------------
// RMSNorm (+scale) + RoPE from f32 projections; emit bf16 hi/lo for Q,K and
// plain bf16 for V. slot 0..7 Q, 8..9 K, 10..11 V.
// ---------------------------------------------------------------------------
__global__ __launch_bounds__(256) void rmsrope(
    const float* __restrict__ qproj, const float* __restrict__ kvproj,
    u16* __restrict__ qh, u16* __restrict__ ql, u16* __restrict__ kh,
    u16* __restrict__ kl, u16* __restrict__ vb,
    const float* __restrict__ q_scale, const float* __restrict__ k_scale) {
  const int t = threadIdx.x;
  const int blk = blockIdx.x;
  const int slot = blk % 12;
  const int bs = blk / 12;
  const int s = bs & 2047;
  const float* src;
  u16 *dsth, *dstl = nullptr;
  const float* scale;
  bool rope;
  if (slot < 8) {
    src = qproj + (size_t)bs * 2048 + slot * 256;
    dsth = qh + (size_t)bs * 2048 + slot * 256;
    dstl = ql + (size_t)bs * 2048 + slot * 256;
    scale = q_scale;
    rope = true;
  } else if (slot < 10) {
    src = kvproj + (size_t)bs * 1024 + (slot - 8) * 256;
    dsth = kh + (size_t)bs * 512 + (slot - 8) * 256;
    dstl = kl + (size_t)bs * 512 + (slot - 8) * 256;
    scale = k_scale;
    rope = true;
  } else {
    src = kvproj + (size_t)bs * 1024 + 512 + (slot - 10) * 256;
    dsth = vb + (size_t)bs * 512 + (slot - 10) * 256;
    scale = nullptr;
    rope = false;
  }
  const float x = src[t];
  float ss = x * x;
#pragma unroll
  for (int off = 32; off; off >>= 1) ss += __shfl_down(ss, off);
  __shared__ float red[4];
  __shared__ float tot;
  if ((t & 63) == 0) red[t >> 6] = ss;
  __syncthreads();
  if (t == 0) tot = red[0] + red[1] + red[2] + red[3];
  __syncthreads();
  const float inv = rsqrtf(tot * (1.f / 256.f) + 1e-6f);
  float n = x * inv;
  if (scale) n *= scale[t];
  if (rope) {
    __shared__ float sh[256];
    sh[t] = n;
    __syncthreads();
    const int fi = t & 127;
    const float invf = expf((float)fi * (-9.210340371976184f / 128.f));
    const float ang = (float)s * invf;
    float sv, cv;
    sincosf(ang, &sv, &cv);
    if (t < 128)
      n = sh[t] * cv - sh[t + 128] * sv;
    else
      n = sh[t] * cv + sh[t - 128] * sv;
  }
  const u16 h = f2bf(n);
  dsth[t] = h;
  if (dstl) dstl[t] = f2bf(n - bf2f(h));
}

// ---------------------------------------------------------------------------
// V transpose: vb [4096][512] bf16 -> vt [4 slabs][256 d][2048 s] bf16.
// ---------------------------------------------------------------------------
__global__ __launch_bounds__(256) void vtrans(const u16* __restrict__ vb,
                                              u16* __restrict__ vt) {
  __shared__ u16 T[64][80];
  const int t = threadIdx.x;
  const int s0 = blockIdx.x * 64;
  const int d0 = blockIdx.y * 64;
  const int slab = blockIdx.z;
  const int b = slab >> 1, kvh = slab & 1;
  const u16* src = vb + (size_t)(b * 2048) * 512 + kvh * 256;
#pragma unroll
  for (int p = 0; p < 2; ++p) {
    const int sl = (t >> 3) + p * 32;
    const int d8 = (t & 7) * 8;
    u16 v[8];
    *(uint4*)v = *(const uint4*)(src + (size_t)(s0 + sl) * 512 + d0 + d8);
#pragma unroll
    for (int j = 0; j < 8; ++j) T[d8 + j][sl] = v[j];
  }
  __syncthreads();
  u16* dst = vt + (size_t)(slab * 256) * 2048;
#pragma unroll
  for (int p = 0; p < 2; ++p) {
    const int dl = (t >> 3) + p * 32;
    const int s8 = (t & 7) * 8;
    *(uint4*)(dst + (size_t)(d0 + dl) * 2048 + s0 + s8) =
        *(const uint4*)&T[dl][s8];
  }
}

// ---------------------------------------------------------------------------
// MFMA flash attention, window 512, causal, scale=1.0. 4 independent waves /
// block, 16 q-rows / wave, 32-key tiles, online softmax. QK^T uses split
// bf16x3 (q and k hi/lo); PV plain bf16.
// ---------------------------------------------------------------------------
__global__ __launch_bounds__(256) void attn_mfma(
    const u16* __restrict__ qhp, const u16* __restrict__ qlp,
    const u16* __restrict__ khp, const u16* __restrict__ klp,
    const u16* __restrict__ vt, u16* __restrict__ attnb) {
  __shared__ u16 Pl[4][16 * 40];
  const int tid = threadIdx.x, lane = tid & 63, wid = tid >> 6;
  const int g = lane >> 4, lc = lane & 15;
  const int blk = blockIdx.x;
  const int qt = blk & 31;
  const int h = (blk >> 5) & 7;
  const int b = blk >> 8;
  const int kvh = h >> 2;
  const int i0 = qt * 64 + wid * 16;

  bf16x8 qfh[8], qfl[8];
  {
    const size_t qo = (size_t)(b * 2048 + i0 + lc) * 2048 + h * 256 + g * 8;
#pragma unroll
    for (int kc = 0; kc < 8; ++kc) {
      qfh[kc] = *(const bf16x8*)(qhp + qo + kc * 32);
      qfl[kc] = *(const bf16x8*)(qlp + qo + kc * 32);
    }
  }
  floatx4 o[16];
#pragma unroll
  for (int d = 0; d < 16; ++d) o[d] = floatx4{0.f, 0.f, 0.f, 0.f};
  float m_[4] = {-1e20f, -1e20f, -1e20f, -1e20f};
  float l_[4] = {0.f, 0.f, 0.f, 0.f};

  const size_t kbo = (size_t)(b * 2048) * 512 + kvh * 256;
  const u16* vbase = vt + (size_t)((b * 2 + kvh) * 256) * 2048;
  u16* pw = Pl[wid];
  int jlo = (i0 - 511) & ~31;
  if (jlo < 0) jlo = 0;
  const int jhi = i0 + 16;

  for (int j0 = jlo; j0 < jhi; j0 += 32) {
    floatx4 s0 = floatx4{0.f, 0.f, 0.f, 0.f};
    floatx4 s1 = floatx4{0.f, 0.f, 0.f, 0.f};
    {
      const size_t k0o = kbo + (size_t)(j0 + lc) * 512 + g * 8;
      const size_t k1o = k0o + 16 * 512;
#pragma unroll
      for (int kc = 0; kc < 8; ++kc) {
        const bf16x8 kh0 = *(const bf16x8*)(khp + k0o + kc * 32);
        const bf16x8 kl0 = *(const bf16x8*)(klp + k0o + kc * 32);
        const bf16x8 kh1 = *(const bf16x8*)(khp + k1o + kc * 32);
        const bf16x8 kl1 = *(const bf16x8*)(klp + k1o + kc * 32);
        s0 = __builtin_amdgcn_mfma_f32_16x16x32_bf16(qfh[kc], kh0, s0, 0, 0, 0);
        s0 = __builtin_amdgcn_mfma_f32_16x16x32_bf16(qfh[kc], kl0, s0, 0, 0, 0);
        s0 = __builtin_amdgcn_mfma_f32_16x16x32_bf16(qfl[kc], kh0, s0, 0, 0, 0);
        s1 = __builtin_amdgcn_mfma_f32_16x16x32_bf16(qfh[kc], kh1, s1, 0, 0, 0);
        s1 = __builtin_amdgcn_mfma_f32_16x16x32_bf16(qfh[kc], kl1, s1, 0, 0, 0);
        s1 = __builtin_amdgcn_mfma_f32_16x16x32_bf16(qfl[kc], kh1, s1, 0, 0, 0);
      }
    }
    if (!(j0 + 31 <= i0 && (i0 + 15) - j0 <= 511)) {
      const int ja = j0 + lc, jb_ = j0 + 16 + lc;
#pragma unroll
      for (int r = 0; r < 4; ++r) {
        const int i = i0 + g * 4 + r;
        if (ja > i || i - ja > 511) s0[r] = -1e30f;
        if (jb_ > i || i - jb_ > 511) s1[r] = -1e30f;
      }
    }
    float rmax[4], p0[4], p1[4], sc[4], rs[4];
#pragma unroll
    for (int r = 0; r < 4; ++r) rmax[r] = fmaxf(s0[r], s1[r]);
#pragma unroll
    for (int off = 1; off < 16; off <<= 1)
#pragma unroll
      for (int r = 0; r < 4; ++r)
        rmax[r] = fmaxf(rmax[r], __shfl_xor(rmax[r], off));
#pragma unroll
    for (int r = 0; r < 4; ++r) {
      const float mn = fmaxf(m_[r], rmax[r]);
      sc[r] = __expf(m_[r] - mn);
      m_[r] = mn;
      p0[r] = __expf(s0[r] - mn);
      p1[r] = __expf(s1[r] - mn);
      rs[r] = p0[r] + p1[r];
    }
#pragma unroll
    for (int off = 1; off < 16; off <<= 1)
#pragma unroll
      for (int r = 0; r < 4; ++r) rs[r] += __shfl_xor(rs[r], off);
#pragma unroll
    for (int r = 0; r < 4; ++r) l_[r] = l_[r] * sc[r] + rs[r];
#pragma unroll
    for (int d = 0; d < 16; ++d)
#pragma unroll
      for (int r = 0; r < 4; ++r) o[d][r] *= sc[r];
#pragma unroll
    for (int r = 0; r < 4; ++r) {
      pw[(g * 4 + r) * 40 + lc] = f2bf(p0[r]);
      pw[(g * 4 + r) * 40 + 16 + lc] = f2bf(p1[r]);
    }
    const bf16x8 pf = *(const bf16x8*)(pw + lc * 40 + g * 8);
    {
      const u16* vp = vbase + (size_t)lc * 2048 + j0 + g * 8;
#pragma unroll
      for (int d = 0; d < 16; ++d)
        o[d] = __builtin_amdgcn_mfma_f32_16x16x32_bf16(
            pf, *(const bf16x8*)(vp + (size_t)d * 16 * 2048), o[d], 0, 0, 0);
    }
  }
  float rinv[4];
#pragma unroll
  for (int r = 0; r < 4; ++r) rinv[r] = 1.f / l_[r];
  u16* ob = attnb + (size_t)(b * 2048 + i0 + g * 4) * 2048 + h * 256 + lc;
#pragma unroll
  for (int d = 0; d < 16; ++d)
#pragma unroll
    for (int r = 0; r < 4; ++r)
      ob[(size_t)r * 2048 + d * 16] = f2bf(o[d][r] * rinv[r]);
}

// ---------------------------------------------------------------------------
// inputs: 0 hidden_states f32 [2,2048,2048], 1 attention_mask (unused: it is
// exactly causal tril, applied analytically with the window band),
// 2 Wq, 3 Wk, 4 Wv, 5 Wo, 6 q_scale, 7 k_scale. out f32 [2,2048,2048].
// ---------------------------------------------------------------------------
extern "C" void kernel_launch(void* const* d_in, const int* in_sizes, int n_in,
                              void* d_out, int out_size, void* d_ws,
                              size_t ws_size, hipStream_t stream) {
  (void)in_sizes;
  (void)n_in;
  (void)out_size;
  (void)ws_size;
  const float* X = (const float*)d_in[0];
  const float* Wq = (const float*)d_in[2];
  const float* Wk = (const float*)d_in[3];
  const float* Wv = (const float*)d_in[4];
  const float* Wo = (const float*)d_in[5];
  const float* qs = (const float*)d_in[6];
  const float* ks = (const float*)d_in[7];
  float* out = (float*)d_out;
  char* ws = (char*)d_ws;

  // ws layout (bytes), lifetime-based reuse. Peak 83,886,080 B.
  float* kvproj = (float*)(ws);              // [0, 16.8M)  -> attnb later
  u16* attnb = (u16*)(ws);
  u16* Xh = (u16*)(ws + 16777216);           // [16.8M, 33.5M) -> qh
  u16* qh = Xh;
  u16* Xl = (u16*)(ws + 33554432);           // [33.5M, 50.3M) -> ql
  u16* ql = Xl;
  u16* Wqth = (u16*)(ws + 50331648);         // [50.3M, 58.7M) -> kh + kl
  u16* kh = Wqth;
  u16* kl = (u16*)(ws + 54525952);
  u16* Wqtl = (u16*)(ws + 58720256);         // [58.7M, 67.1M) -> vb + vt
  u16* vb = Wqtl;
  u16* vt = (u16*)(ws + 62914560);
  u16* Wkvth = (u16*)(ws + 67108864);        // [67.1M, 71.3M)
  u16* Wkvtl = (u16*)(ws + 71303168);        // [71.3M, 75.5M)
  u16* Wot = (u16*)(ws + 75497472);          // [75.5M, 83.9M)
  float* qproj = out;                        // d_out doubles as f32 scratch

  splitbf<<<4096, 256, 0, stream>>>(X, Xh, Xl, 1048576);
  wtrans_s<<<dim3(32, 32), 256, 0, stream>>>(Wq, Wqth, Wqtl, 2048, 2048);
  wtrans_s<<<dim3(8, 32), 256, 0, stream>>>(Wk, Wkvth, Wkvtl, 2048, 512);
  wtrans_s<<<dim3(8, 32), 256, 0, stream>>>(Wv, Wkvth + (size_t)512 * 2048,
                                            Wkvtl + (size_t)512 * 2048, 2048,
                                            512);
  wtrans<<<dim3(32, 32), 256, 0, stream>>>(Wo, Wot, 2048, 2048);
  gemm_bf16s<<<dim3(16, 32), 256, 0, stream>>>(Xh, Xl, Wqth, Wqtl, qproj, 4096,
                                               2048, 2048);
  gemm_bf16s<<<dim3(8, 32), 256, 0, stream>>>(Xh, Xl, Wkvth, Wkvtl, kvproj,
                                              4096, 1024, 2048);
  rmsrope<<<4096 * 12, 256, 0, stream>>>(qproj, kvproj, qh, ql, kh, kl, vb, qs,
                                         ks);
  vtrans<<<dim3(32, 4, 4), 256, 0, stream>>>(vb, vt);
  attn_mfma<<<512, 256, 0, stream>>>(qh, ql, kh, kl, vt, attnb);
  gemm_bf16<<<dim3(16, 32), 256, 0, stream>>>(attnb, Wot, out, 4096, 2048,
                                              2048);
}

// Round 4
// 423.730 us; speedup vs baseline: 6.4377x; 1.2333x over previous
//
#include <hip/hip_runtime.h>
#include <cstdint>
#include <cstddef>

typedef unsigned short u16;
typedef float floatx4 __attribute__((ext_vector_type(4)));
typedef __bf16 bf16x8 __attribute__((ext_vector_type(8)));

__device__ __forceinline__ u16 f2bf(float f) {
  union { float f; unsigned u; } v;
  v.f = f;
  unsigned u = v.u;
  u += 0x7FFFu + ((u >> 16) & 1u);
  return (u16)(u >> 16);
}
__device__ __forceinline__ float bf2f(u16 h) {
  union { unsigned u; float f; } v;
  v.u = ((unsigned)h) << 16;
  return v.f;
}

#define GLL16(g, l)                                                       \
  __builtin_amdgcn_global_load_lds(                                       \
      (const __attribute__((address_space(1))) void*)(g),                 \
      (__attribute__((address_space(3))) void*)(l), 16, 0, 0)

// ---------------------------------------------------------------------------
// split f32 -> (hi, lo) bf16 pair, 8 elems/thread. x ~= hi + lo.
// ---------------------------------------------------------------------------
__global__ __launch_bounds__(256) void splitbf(const float* __restrict__ in,
                                               u16* __restrict__ oh,
                                               u16* __restrict__ ol, int n8) {
  int idx = blockIdx.x * 256 + threadIdx.x;
  if (idx >= n8) return;
  float x[8];
  *(float4*)&x[0] = *(const float4*)(in + (size_t)idx * 8);
  *(float4*)&x[4] = *(const float4*)(in + (size_t)idx * 8 + 4);
  u16 h[8], l[8];
#pragma unroll
  for (int j = 0; j < 8; ++j) {
    h[j] = f2bf(x[j]);
    l[j] = f2bf(x[j] - bf2f(h[j]));
  }
  *(uint4*)(oh + (size_t)idx * 8) = *(const uint4*)h;
  *(uint4*)(ol + (size_t)idx * 8) = *(const uint4*)l;
}

// ---------------------------------------------------------------------------
// transpose f32 [R][C] -> bf16 hi/lo [C][R].  R,C % 64 == 0.
// ---------------------------------------------------------------------------
__global__ __launch_bounds__(256) void wtrans_s(const float* __restrict__ in,
                                                u16* __restrict__ oh,
                                                u16* __restrict__ ol, int R,
                                                int C) {
  __shared__ float T[64][65];
  const int t = threadIdx.x;
  const int r0 = blockIdx.y * 64;
  const int c0 = blockIdx.x * 64;
#pragma unroll
  for (int p = 0; p < 4; ++p) {
    const int rl = (t >> 4) + p * 16;
    const int c4 = (t & 15) * 4;
    float4 v = *(const float4*)(in + (size_t)(r0 + rl) * C + c0 + c4);
    T[c4 + 0][rl] = v.x;
    T[c4 + 1][rl] = v.y;
    T[c4 + 2][rl] = v.z;
    T[c4 + 3][rl] = v.w;
  }
  __syncthreads();
#pragma unroll
  for (int p = 0; p < 2; ++p) {
    const int cl = (t >> 3) + p * 32;
    const int r8 = (t & 7) * 8;
    u16 h[8], l[8];
#pragma unroll
    for (int j = 0; j < 8; ++j) {
      const float x = T[cl][r8 + j];
      h[j] = f2bf(x);
      l[j] = f2bf(x - bf2f(h[j]));
    }
    *(uint4*)(oh + (size_t)(c0 + cl) * R + r0 + r8) = *(const uint4*)h;
    *(uint4*)(ol + (size_t)(c0 + cl) * R + r0 + r8) = *(const uint4*)l;
  }
}

// ---------------------------------------------------------------------------
// transpose f32 [R][C] -> bf16 [C][R] (hi only), for Wo.
// ---------------------------------------------------------------------------
__global__ __launch_bounds__(256) void wtrans(const float* __restrict__ in,
                                              u16* __restrict__ out, int R,
                                              int C) {
  __shared__ u16 T[64][80];
  const int t = threadIdx.x;
  const int r0 = blockIdx.y * 64;
  const int c0 = blockIdx.x * 64;
#pragma unroll
  for (int p = 0; p < 4; ++p) {
    const int rl = (t >> 4) + p * 16;
    const int c4 = (t & 15) * 4;
    float4 v = *(const float4*)(in + (size_t)(r0 + rl) * C + c0 + c4);
    T[c4 + 0][rl] = f2bf(v.x);
    T[c4 + 1][rl] = f2bf(v.y);
    T[c4 + 2][rl] = f2bf(v.z);
    T[c4 + 3][rl] = f2bf(v.w);
  }
  __syncthreads();
#pragma unroll
  for (int p = 0; p < 2; ++p) {
    const int cl = (t >> 3) + p * 32;
    const int r8 = (t & 7) * 8;
    *(uint4*)(out + (size_t)(c0 + cl) * R + r0 + r8) =
        *(const uint4*)&T[cl][r8];
  }
}

// ---------------------------------------------------------------------------
// SPLIT bf16x3 MFMA GEMM: C f32 = (Ah+Al)[M,K] x (Bh+Bl)^T, B given as [N,K].
// ---------------------------------------------------------------------------
__global__ __launch_bounds__(256) void gemm_bf16s(
    const u16* __restrict__ Ah, const u16* __restrict__ Al,
    const u16* __restrict__ Bh, const u16* __restrict__ Bl,
    float* __restrict__ C, int M, int N, int K) {
  __shared__ u16 Ash[4096], Asl[4096], Bsh[4096], Bsl[4096];
  const int tid = threadIdx.x;
  const int lane = tid & 63;
  const int wid = tid >> 6;
  const int g = lane >> 4, lc = lane & 15;
  const int bm = blockIdx.y * 128, bn = blockIdx.x * 128;
  const int wr = (wid >> 1) * 64, wc = (wid & 1) * 64;
  const size_t aoff = (size_t)(bm + (tid >> 2)) * K + (tid & 3) * 8;
  const size_t boff = (size_t)(bn + (tid >> 2)) * K + (tid & 3) * 8;

  floatx4 acc[4][4];
#pragma unroll
  for (int i = 0; i < 4; ++i)
#pragma unroll
    for (int j = 0; j < 4; ++j) acc[i][j] = floatx4{0.f, 0.f, 0.f, 0.f};

  for (int k0 = 0; k0 < K; k0 += 32) {
    __syncthreads();
    GLL16(Ah + aoff + k0, Ash + tid * 8);
    GLL16(Ah + aoff + (size_t)64 * K + k0, Ash + 2048 + tid * 8);
    GLL16(Al + aoff + k0, Asl + tid * 8);
    GLL16(Al + aoff + (size_t)64 * K + k0, Asl + 2048 + tid * 8);
    GLL16(Bh + boff + k0, Bsh + tid * 8);
    GLL16(Bh + boff + (size_t)64 * K + k0, Bsh + 2048 + tid * 8);
    GLL16(Bl + boff + k0, Bsl + tid * 8);
    GLL16(Bl + boff + (size_t)64 * K + k0, Bsl + 2048 + tid * 8);
    __syncthreads();
    bf16x8 afh[4], afl[4], bfh[4], bfl[4];
#pragma unroll
    for (int m = 0; m < 4; ++m) {
      afh[m] = *(const bf16x8*)(Ash + (wr + m * 16 + lc) * 32 + g * 8);
      afl[m] = *(const bf16x8*)(Asl + (wr + m * 16 + lc) * 32 + g * 8);
    }
#pragma unroll
    for (int n = 0; n < 4; ++n) {
      bfh[n] = *(const bf16x8*)(Bsh + (wc + n * 16 + lc) * 32 + g * 8);
      bfl[n] = *(const bf16x8*)(Bsl + (wc + n * 16 + lc) * 32 + g * 8);
    }
#pragma unroll
    for (int m = 0; m < 4; ++m)
#pragma unroll
      for (int n = 0; n < 4; ++n) {
        acc[m][n] = __builtin_amdgcn_mfma_f32_16x16x32_bf16(afh[m], bfh[n],
                                                            acc[m][n], 0, 0, 0);
        acc[m][n] = __builtin_amdgcn_mfma_f32_16x16x32_bf16(afh[m], bfl[n],
                                                            acc[m][n], 0, 0, 0);
        acc[m][n] = __builtin_amdgcn_mfma_f32_16x16x32_bf16(afl[m], bfh[n],
                                                            acc[m][n], 0, 0, 0);
      }
  }
#pragma unroll
  for (int m = 0; m < 4; ++m)
#pragma unroll
    for (int n = 0; n < 4; ++n) {
      float* Cp = C + (size_t)(bm + wr + m * 16 + g * 4) * N + bn + wc +
                  n * 16 + lc;
#pragma unroll
      for (int r = 0; r < 4; ++r) Cp[(size_t)r * N] = acc[m][n][r];
    }
}

// ---------------------------------------------------------------------------
// plain bf16 MFMA GEMM (O-proj): C f32 = A[M,K] x Bt[N,K]^T.
// ---------------------------------------------------------------------------
__global__ __launch_bounds__(256) void gemm_bf16(const u16* __restrict__ A,
                                                 const u16* __restrict__ Bt,
                                                 float* __restrict__ C, int M,
                                                 int N, int K) {
  __shared__ u16 As[4096];
  __shared__ u16 Bs[4096];
  const int tid = threadIdx.x;
  const int lane = tid & 63;
  const int wid = tid >> 6;
  const int g = lane >> 4, lc = lane & 15;
  const int bm = blockIdx.y * 128, bn = blockIdx.x * 128;
  const int wr = (wid >> 1) * 64, wc = (wid & 1) * 64;
  const u16* Ag = A + (size_t)(bm + (tid >> 2)) * K + (tid & 3) * 8;
  const u16* Bg = Bt + (size_t)(bn + (tid >> 2)) * K + (tid & 3) * 8;

  floatx4 acc[4][4];
#pragma unroll
  for (int i = 0; i < 4; ++i)
#pragma unroll
    for (int j = 0; j < 4; ++j) acc[i][j] = floatx4{0.f, 0.f, 0.f, 0.f};

  for (int k0 = 0; k0 < K; k0 += 32) {
    __syncthreads();
    GLL16(Ag + k0, As + tid * 8);
    GLL16(Ag + (size_t)64 * K + k0, As + 2048 + tid * 8);
    GLL16(Bg + k0, Bs + tid * 8);
    GLL16(Bg + (size_t)64 * K + k0, Bs + 2048 + tid * 8);
    __syncthreads();
    bf16x8 af[4], bfr[4];
#pragma unroll
    for (int m = 0; m < 4; ++m)
      af[m] = *(const bf16x8*)(As + (wr + m * 16 + lc) * 32 + g * 8);
#pragma unroll
    for (int n = 0; n < 4; ++n)
      bfr[n] = *(const bf16x8*)(Bs + (wc + n * 16 + lc) * 32 + g * 8);
#pragma unroll
    for (int m = 0; m < 4; ++m)
#pragma unroll
      for (int n = 0; n < 4; ++n)
        acc[m][n] = __builtin_amdgcn_mfma_f32_16x16x32_bf16(af[m], bfr[n],
                                                            acc[m][n], 0, 0, 0);
  }
#pragma unroll
  for (int m = 0; m < 4; ++m)
#pragma unroll
    for (int n = 0; n < 4; ++n) {
      float* Cp = C + (size_t)(bm + wr + m * 16 + g * 4) * N + bn + wc +
                  n * 16 + lc;
#pragma unroll
      for (int r = 0; r < 4; ++r) Cp[(size_t)r * N] = acc[m][n][r];
    }
}

// ---------------------------------------------------------------------------
// RMSNorm (+scale) + RoPE; emits MFMA-fragment-PACKED bf16:
//  Q (hi/lo): qpack[b][h][tile16][kc][lc][g][e]  (granule = 16B, 8KB/tile)
//  K (hi/lo): kpack[b][kvh][tile32][kc][hi][lc][g][e]  (16KB/tile)
//  V:         plain rows vrows[b][kvh][s][256] (packed later by vpack_k)
// slot 0..7 Q, 8..9 K, 10..11 V.
// ---------------------------------------------------------------------------
__global__ __launch_bounds__(256) void rmsrope(
    const float* __restrict__ qproj, const float* __restrict__ kvproj,
    u16* __restrict__ qph, u16* __restrict__ qpl, u16* __restrict__ kph,
    u16* __restrict__ kpl, u16* __restrict__ vrows,
    const float* __restrict__ q_scale, const float* __restrict__ k_scale) {
  const int t = threadIdx.x;
  const int blk = blockIdx.x;
  const int slot = blk % 12;
  const int bs = blk / 12;
  const int b = bs >> 11;
  const int s = bs & 2047;
  const float* src;
  const float* scale;
  bool rope;
  if (slot < 8) {
    src = qproj + (size_t)bs * 2048 + slot * 256;
    scale = q_scale;
    rope = true;
  } else if (slot < 10) {
    src = kvproj + (size_t)bs * 1024 + (slot - 8) * 256;
    scale = k_scale;
    rope = true;
  } else {
    src = kvproj + (size_t)bs * 1024 + 512 + (slot - 10) * 256;
    scale = nullptr;
    rope = false;
  }
  const float x = src[t];
  float ss = x * x;
#pragma unroll
  for (int off = 32; off; off >>= 1) ss += __shfl_down(ss, off);
  __shared__ float red[4];
  __shared__ float tot;
  if ((t & 63) == 0) red[t >> 6] = ss;
  __syncthreads();
  if (t == 0) tot = red[0] + red[1] + red[2] + red[3];
  __syncthreads();
  const float inv = rsqrtf(tot * (1.f / 256.f) + 1e-6f);
  float n = x * inv;
  if (scale) n *= scale[t];
  if (rope) {
    __shared__ float sh[256];
    sh[t] = n;
    __syncthreads();
    const int fi = t & 127;
    const float invf = expf((float)fi * (-9.210340371976184f / 128.f));
    const float ang = (float)s * invf;
    float sv, cv;
    sincosf(ang, &sv, &cv);
    if (t < 128)
      n = sh[t] * cv - sh[t + 128] * sv;
    else
      n = sh[t] * cv + sh[t - 128] * sv;
  }
  const int kc = t >> 5, gg = (t >> 3) & 3, e = t & 7;
  if (slot < 8) {
    const size_t off = ((size_t)(b * 8 + slot) * 128 + (s >> 4)) * 4096 +
                       kc * 512 + (s & 15) * 32 + gg * 8 + e;
    const u16 hh = f2bf(n);
    qph[off] = hh;
    qpl[off] = f2bf(n - bf2f(hh));
  } else if (slot < 10) {
    const int kvh = slot - 8;
    const size_t off = ((size_t)(b * 2 + kvh) * 64 + (s >> 5)) * 8192 +
                       kc * 1024 + ((s >> 4) & 1) * 512 + (s & 15) * 32 +
                       gg * 8 + e;
    const u16 hh = f2bf(n);
    kph[off] = hh;
    kpl[off] = f2bf(n - bf2f(hh));
  } else {
    const int kvh = slot - 10;
    vrows[((size_t)(b * 2 + kvh) * 2048 + s) * 256 + t] = f2bf(n);
  }
}

// ---------------------------------------------------------------------------
// V pack: vrows [slab][2048][256] -> vpack[slab][tile32][d_iter][lc][g][e]
// granule content: V[tile*32 + g*8 + e][d_iter*16 + lc]. 16KB/tile.
// ---------------------------------------------------------------------------
__global__ __launch_bounds__(256) void vpack_k(const u16* __restrict__ vrows,
                                               u16* __restrict__ vpk) {
  __shared__ u16 T[32][264];
  const int t = threadIdx.x;
  const int tile = blockIdx.x;
  const int slab = blockIdx.y;
  const u16* src = vrows + ((size_t)slab * 2048 + tile * 32) * 256;
#pragma unroll
  for (int p = 0; p < 2; ++p) {
    const int row = (t >> 4) + p * 16;
    const int c = (t & 15) * 16;
    *(uint4*)&T[row][c] = *(const uint4*)(src + (size_t)row * 256 + c);
    *(uint4*)&T[row][c + 8] = *(const uint4*)(src + (size_t)row * 256 + c + 8);
  }
  __syncthreads();
  u16* dst = vpk + ((size_t)slab * 64 + tile) * 8192;
#pragma unroll
  for (int p = 0; p < 4; ++p) {
    const int gi = t * 4 + p;
    const int di = gi >> 6, lcc = (gi >> 2) & 15, gg = gi & 3;
    u16 tmp[8];
#pragma unroll
    for (int e = 0; e < 8; ++e) tmp[e] = T[gg * 8 + e][di * 16 + lcc];
    *(uint4*)(dst + (size_t)gi * 8) = *(const uint4*)tmp;
  }
}

// ---------------------------------------------------------------------------
// MFMA flash attention v2: block = 64 q-rows (4 waves x 16), K/V tiles staged
// in LDS via coalesced global_load_lds from packed buffers, shared across
// waves. Conflict-free fragment reads (per-lane base + imm offset).
// Sliding window 512, causal, scale=1.0. Split bf16x3 QK; plain bf16 PV.
// ---------------------------------------------------------------------------
__global__ __launch_bounds__(256) void attn_mfma2(
    const u16* __restrict__ qph, const u16* __restrict__ qpl,
    const u16* __restrict__ kph, const u16* __restrict__ kpl,
    const u16* __restrict__ vpk, u16* __restrict__ attnb) {
  __shared__ u16 Kh[8192], Kl[8192], Vt[8192];
  __shared__ u16 Pl[4][16 * 40];
  const int tid = threadIdx.x, lane = tid & 63, wid = tid >> 6;
  const int g = lane >> 4, lc = lane & 15;
  const int lbu = lc * 32 + g * 8;  // per-lane fragment base (u16 units)
  const int blk = blockIdx.x;
  const int qt = blk & 31;
  const int h = (blk >> 5) & 7;
  const int b = blk >> 8;
  const int kvh = h >> 2;
  const int i0b = qt * 64;
  const int i0 = i0b + wid * 16;

  bf16x8 qfh[8], qfl[8];
  {
    const size_t qtb =
        ((size_t)(b * 8 + h) * 128 + (i0 >> 4)) * 4096 + lbu;
#pragma unroll
    for (int kc = 0; kc < 8; ++kc) {
      qfh[kc] = *(const bf16x8*)(qph + qtb + kc * 512);
      qfl[kc] = *(const bf16x8*)(qpl + qtb + kc * 512);
    }
  }
  floatx4 o[16];
#pragma unroll
  for (int d = 0; d < 16; ++d) o[d] = floatx4{0.f, 0.f, 0.f, 0.f};
  float m_[4] = {-1e20f, -1e20f, -1e20f, -1e20f};
  float l_[4] = {0.f, 0.f, 0.f, 0.f};
  u16* pw = Pl[wid];

  const int jlo = (i0b >= 512) ? i0b - 512 : 0;
  const int nt = (i0b + 64 - jlo) >> 5;
  const size_t kvbase = (size_t)(b * 2 + kvh) * 64;

  for (int t = 0; t < nt; ++t) {
    const int j0 = jlo + t * 32;
    const size_t tb = (kvbase + (j0 >> 5)) * 8192;
    __syncthreads();
#pragma unroll
    for (int i = 0; i < 4; ++i) {
      GLL16(kph + tb + i * 2048 + tid * 8, Kh + i * 2048 + tid * 8);
      GLL16(kpl + tb + i * 2048 + tid * 8, Kl + i * 2048 + tid * 8);
      GLL16(vpk + tb + i * 2048 + tid * 8, Vt + i * 2048 + tid * 8);
    }
    __syncthreads();
    if (j0 > i0 + 15 || j0 + 31 < i0 - 511) continue;  // dead tile, this wave

    floatx4 s0 = floatx4{0.f, 0.f, 0.f, 0.f};
    floatx4 s1 = floatx4{0.f, 0.f, 0.f, 0.f};
#pragma unroll
    for (int kc = 0; kc < 8; ++kc) {
      const bf16x8 kh0 = *(const bf16x8*)(Kh + kc * 1024 + lbu);
      const bf16x8 kh1 = *(const bf16x8*)(Kh + kc * 1024 + 512 + lbu);
      const bf16x8 kl0 = *(const bf16x8*)(Kl + kc * 1024 + lbu);
      const bf16x8 kl1 = *(const bf16x8*)(Kl + kc * 1024 + 512 + lbu);
      s0 = __builtin_amdgcn_mfma_f32_16x16x32_bf16(qfh[kc], kh0, s0, 0, 0, 0);
      s0 = __builtin_amdgcn_mfma_f32_16x16x32_bf16(qfh[kc], kl0, s0, 0, 0, 0);
      s0 = __builtin_amdgcn_mfma_f32_16x16x32_bf16(qfl[kc], kh0, s0, 0, 0, 0);
      s1 = __builtin_amdgcn_mfma_f32_16x16x32_bf16(qfh[kc], kh1, s1, 0, 0, 0);
      s1 = __builtin_amdgcn_mfma_f32_16x16x32_bf16(qfh[kc], kl1, s1, 0, 0, 0);
      s1 = __builtin_amdgcn_mfma_f32_16x16x32_bf16(qfl[kc], kh1, s1, 0, 0, 0);
    }
    if (!(j0 + 31 <= i0 && (i0 + 15) - j0 <= 511)) {
      const int ja = j0 + lc, jb_ = j0 + 16 + lc;
#pragma unroll
      for (int r = 0; r < 4; ++r) {
        const int i = i0 + g * 4 + r;
        if (ja > i || i - ja > 511) s0[r] = -1e30f;
        if (jb_ > i || i - jb_ > 511) s1[r] = -1e30f;
      }
    }
    float rmax[4], p0[4], p1[4], sc[4], rs[4];
#pragma unroll
    for (int r = 0; r < 4; ++r) rmax[r] = fmaxf(s0[r], s1[r]);
#pragma unroll
    for (int off = 1; off < 16; off <<= 1)
#pragma unroll
      for (int r = 0; r < 4; ++r)
        rmax[r] = fmaxf(rmax[r], __shfl_xor(rmax[r], off));
#pragma unroll
    for (int r = 0; r < 4; ++r) {
      const float mn = fmaxf(m_[r], rmax[r]);
      sc[r] = __expf(m_[r] - mn);
      m_[r] = mn;
      p0[r] = __expf(s0[r] - mn);
      p1[r] = __expf(s1[r] - mn);
      rs[r] = p0[r] + p1[r];
    }
#pragma unroll
    for (int off = 1; off < 16; off <<= 1)
#pragma unroll
      for (int r = 0; r < 4; ++r) rs[r] += __shfl_xor(rs[r], off);
#pragma unroll
    for (int r = 0; r < 4; ++r) l_[r] = l_[r] * sc[r] + rs[r];
#pragma unroll
    for (int d = 0; d < 16; ++d)
#pragma unroll
      for (int r = 0; r < 4; ++r) o[d][r] *= sc[r];
#pragma unroll
    for (int r = 0; r < 4; ++r) {
      pw[(g * 4 + r) * 40 + lc] = f2bf(p0[r]);
      pw[(g * 4 + r) * 40 + 16 + lc] = f2bf(p1[r]);
    }
    const bf16x8 pf = *(const bf16x8*)(pw + lc * 40 + g * 8);
#pragma unroll
    for (int d = 0; d < 16; ++d)
      o[d] = __builtin_amdgcn_mfma_f32_16x16x32_bf16(
          pf, *(const bf16x8*)(Vt + d * 512 + lbu), o[d], 0, 0, 0);
  }
  float rinv[4];
#pragma unroll
  for (int r = 0; r < 4; ++r) rinv[r] = 1.f / l_[r];
  u16* ob = attnb + (size_t)(b * 2048 + i0 + g * 4) * 2048 + h * 256 + lc;
#pragma unroll
  for (int d = 0; d < 16; ++d)
#pragma unroll
    for (int r = 0; r < 4; ++r)
      ob[(size_t)r * 2048 + d * 16] = f2bf(o[d][r] * rinv[r]);
}

// ---------------------------------------------------------------------------
// inputs: 0 hidden_states f32, 1 attention_mask (unused: exactly causal tril,
// applied analytically with the window band), 2 Wq, 3 Wk, 4 Wv, 5 Wo,
// 6 q_scale, 7 k_scale. out f32 [2,2048,2048].
// ---------------------------------------------------------------------------
extern "C" void kernel_launch(void* const* d_in, const int* in_sizes, int n_in,
                              void* d_out, int out_size, void* d_ws,
                              size_t ws_size, hipStream_t stream) {
  (void)in_sizes;
  (void)n_in;
  (void)out_size;
  (void)ws_size;
  const float* X = (const float*)d_in[0];
  const float* Wq = (const float*)d_in[2];
  const float* Wk = (const float*)d_in[3];
  const float* Wv = (const float*)d_in[4];
  const float* Wo = (const float*)d_in[5];
  const float* qs = (const float*)d_in[6];
  const float* ks = (const float*)d_in[7];
  float* out = (float*)d_out;
  char* ws = (char*)d_ws;

  // ws layout (bytes), lifetime-based reuse. Peak 83,886,080 B.
  float* kvproj = (float*)(ws);        // [0, 16.8M)       -> attnb later
  u16* attnb = (u16*)(ws);
  u16* Xh = (u16*)(ws + 16777216);     // [16.8M, 33.5M)   -> qph
  u16* qph = Xh;
  u16* Xl = (u16*)(ws + 33554432);     // [33.5M, 50.3M)   -> qpl
  u16* qpl = Xl;
  u16* Wqth = (u16*)(ws + 50331648);   // [50.3M, 58.7M)   -> kph + kpl
  u16* kph = Wqth;
  u16* kpl = (u16*)(ws + 54525952);
  u16* Wqtl = (u16*)(ws + 58720256);   // [58.7M, 67.1M)   -> vrows + vpack
  u16* vrows = Wqtl;
  u16* vpk = (u16*)(ws + 62914560);
  u16* Wkvth = (u16*)(ws + 67108864);  // [67.1M, 71.3M)
  u16* Wkvtl = (u16*)(ws + 71303168);  // [71.3M, 75.5M)
  u16* Wot = (u16*)(ws + 75497472);    // [75.5M, 83.9M)
  float* qproj = out;                  // d_out doubles as f32 scratch

  splitbf<<<4096, 256, 0, stream>>>(X, Xh, Xl, 1048576);
  wtrans_s<<<dim3(32, 32), 256, 0, stream>>>(Wq, Wqth, Wqtl, 2048, 2048);
  wtrans_s<<<dim3(8, 32), 256, 0, stream>>>(Wk, Wkvth, Wkvtl, 2048, 512);
  wtrans_s<<<dim3(8, 32), 256, 0, stream>>>(Wv, Wkvth + (size_t)512 * 2048,
                                            Wkvtl + (size_t)512 * 2048, 2048,
                                            512);
  wtrans<<<dim3(32, 32), 256, 0, stream>>>(Wo, Wot, 2048, 2048);
  gemm_bf16s<<<dim3(16, 32), 256, 0, stream>>>(Xh, Xl, Wqth, Wqtl, qproj, 4096,
                                               2048, 2048);
  gemm_bf16s<<<dim3(8, 32), 256, 0, stream>>>(Xh, Xl, Wkvth, Wkvtl, kvproj,
                                              4096, 1024, 2048);
  rmsrope<<<4096 * 12, 256, 0, stream>>>(qproj, kvproj, qph, qpl, kph, kpl,
                                         vrows, qs, ks);
  vpack_k<<<dim3(64, 4), 256, 0, stream>>>(vrows, vpk);
  attn_mfma2<<<512, 256, 0, stream>>>(qph, qpl, kph, kpl, vpk, attnb);
  gemm_bf16<<<dim3(16, 32), 256, 0, stream>>>(attnb, Wot, out, 4096, 2048,
                                              2048);
}